// Round 1
// baseline (156.379 us; speedup 1.0000x reference)
//
#include <hip/hip_runtime.h>

// Problem: B=2048, N=512, C=64, L=2, O=8192
//   connections = argmax_c weights[c,l,o]          -> [L,O]
//   sel[l,o]    = indices[connections[l,o], l, o]  -> [L,O]
//   out[b,l,o]  = x[b, sel[l,o]]                   -> [B,L,O] fp32 (128 MiB)
//
// Floor: 128 MiB output writes @ ~6.3 TB/s ~= 21 us (+ ~79.5 us harness poison
// fill inside the timed region). R1 theory: gather was at ~2 TB/s because the
// grid gave only 4 blocks/CU (16 waves, 50% occupancy) and stores sit behind
// sel-load -> LDS-gather dependency chains. Fix: 2048 blocks (8/CU, 32 waves),
// hoist sel to registers, row-contiguous store order, nontemporal stores.

#define BB 2048
#define NN 512
#define CC 64
#define LL 2
#define OO 8192
#define LO (LL * OO)                   // 16384
#define ROWS 8                         // batch rows per block
#define CHUNK 2048                     // lo elements per block
#define NCHUNK (LO / CHUNK)            // 8  -> grid = 256*8 = 2048 blocks
#define ITERS (CHUNK / (256 * 4))      // 2 int4/float4 iterations per thread

typedef float f32x4 __attribute__((ext_vector_type(4)));
typedef int   i32x4 __attribute__((ext_vector_type(4)));

__global__ void sel_kernel(const float* __restrict__ weights,
                           const int* __restrict__ indices,
                           int* __restrict__ sel) {
    int t = blockIdx.x * blockDim.x + threadIdx.x;  // t = l*O + o
    if (t >= LO) return;
    float best = weights[t];
    int bestc = 0;
#pragma unroll 16
    for (int c = 1; c < CC; ++c) {
        float w = weights[(size_t)c * LO + t];
        if (w > best) { best = w; bestc = c; }  // strict > keeps first-max (JAX argmax)
    }
    sel[t] = indices[(size_t)bestc * LO + t];
}

__global__ void __launch_bounds__(256, 8)
gather_kernel(const float* __restrict__ x,
              const int* __restrict__ sel,
              float* __restrict__ out) {
    __shared__ float xrows[ROWS * NN];   // 16 KiB: 8 contiguous batch rows of x

    const int chunk = blockIdx.x % NCHUNK;       // lo chunk  [0, 8)
    const int rg    = blockIdx.x / NCHUNK;       // row group [0, 256)
    const int b0    = rg * ROWS;

    // Issue sel loads first (independent of LDS) so they overlap x staging.
    i32x4 s[ITERS];
    const int* selp = sel + chunk * CHUNK;
#pragma unroll
    for (int i = 0; i < ITERS; ++i)
        s[i] = *reinterpret_cast<const i32x4*>(selp + i * 1024 + threadIdx.x * 4);

    // Stage 8 contiguous x rows (4096 floats) with coalesced float4 loads.
    const f32x4* xp4 = reinterpret_cast<const f32x4*>(x + (size_t)b0 * NN);
    f32x4* sh4 = reinterpret_cast<f32x4*>(xrows);
#pragma unroll
    for (int i = 0; i < (ROWS * NN / 4) / 256; ++i)   // 4 iterations
        sh4[i * 256 + threadIdx.x] = xp4[i * 256 + threadIdx.x];
    __syncthreads();

    float* op = out + (size_t)b0 * LO + chunk * CHUNK;

    // Row-major store order: each wave walks a contiguous 8 KiB run per row,
    // nontemporal so the 128 MiB stream doesn't churn L2 dirty lines.
#pragma unroll
    for (int r = 0; r < ROWS; ++r) {
        const float* row = xrows + r * NN;
        float* orow = op + (size_t)r * LO;
#pragma unroll
        for (int i = 0; i < ITERS; ++i) {
            const int base = i * 1024 + threadIdx.x * 4;
            f32x4 v;
            v.x = row[s[i].x];
            v.y = row[s[i].y];
            v.z = row[s[i].z];
            v.w = row[s[i].w];
            __builtin_nontemporal_store(v, reinterpret_cast<f32x4*>(orow + base));
        }
    }
}

extern "C" void kernel_launch(void* const* d_in, const int* in_sizes, int n_in,
                              void* d_out, int out_size, void* d_ws, size_t ws_size,
                              hipStream_t stream) {
    const float* x       = (const float*)d_in[0];   // [B, N]
    const float* weights = (const float*)d_in[1];   // [C, L, O]
    const int*   indices = (const int*)d_in[2];     // [C, L, O] (int32: JAX x64 off)
    float*       out     = (float*)d_out;           // [B, L, O]
    int*         sel     = (int*)d_ws;              // [L*O] scratch (64 KiB)

    sel_kernel<<<LO / 256, 256, 0, stream>>>(weights, indices, sel);
    gather_kernel<<<(BB / ROWS) * NCHUNK, 256, 0, stream>>>(x, sel, out);
}

// Round 2
// 154.941 us; speedup vs baseline: 1.0093x; 1.0093x over previous
//
#include <hip/hip_runtime.h>

// Problem: B=2048, N=512, C=64, L=2, O=8192
//   connections = argmax_c weights[c,l,o]          -> [L,O]
//   sel[l,o]    = indices[connections[l,o], l, o]  -> [L,O]
//   out[b,l,o]  = x[b, sel[l,o]]                   -> [B,L,O] fp32 (128 MiB)
//
// Floor: 128 MiB output writes @ ~6.3 TB/s ~= 21 us. Timed region also holds a
// ~84 us 512 MiB harness poison fill + reset dispatches (fixed).
// R2 theory: R0/R1 both neutral => the invariant is the per-store LDS wait
// chain (4 ds_read -> lgkmcnt(0) -> store, x16/wave) exposing ~120cy LDS
// latency per store. Fix: batch ALL 32 gathers (shared vaddr, constant
// offset:r*2048 per row) before any store; stores then issue back-to-back.

#define BB 2048
#define NN 512
#define CC 64
#define LL 2
#define OO 8192
#define LO (LL * OO)                   // 16384
#define ROWS 8                         // batch rows per block
#define CHUNK 2048                     // lo elements per block
#define NCHUNK (LO / CHUNK)            // 8  -> grid = 256*8 = 2048 blocks
#define ITERS (CHUNK / (256 * 4))      // 2 int4/float4 iterations per thread

typedef float f32x4 __attribute__((ext_vector_type(4)));
typedef int   i32x4 __attribute__((ext_vector_type(4)));

__global__ void __launch_bounds__(64)
sel_kernel(const float* __restrict__ weights,
           const int* __restrict__ indices,
           int* __restrict__ sel) {
    int t = blockIdx.x * 64 + threadIdx.x;          // t = l*O + o; 256 blocks
    float best = weights[t];
    int bestc = 0;
#pragma unroll 16
    for (int c = 1; c < CC; ++c) {
        float w = weights[(size_t)c * LO + t];
        if (w > best) { best = w; bestc = c; }      // strict > = first-max (JAX argmax)
    }
    sel[t] = indices[(size_t)bestc * LO + t];
}

__global__ void __launch_bounds__(256, 8)
gather_kernel(const float* __restrict__ x,
              const int* __restrict__ sel,
              float* __restrict__ out) {
    __shared__ float xrows[ROWS * NN];   // 16 KiB: 8 contiguous batch rows of x

    const int chunk = blockIdx.x % NCHUNK;       // lo chunk  [0, 8)
    const int rg    = blockIdx.x / NCHUNK;       // row group [0, 256)
    const int b0    = rg * ROWS;

    // Issue sel loads first (independent of LDS) so they overlap x staging.
    i32x4 s[ITERS];
    const int* selp = sel + chunk * CHUNK;
#pragma unroll
    for (int i = 0; i < ITERS; ++i)
        s[i] = *reinterpret_cast<const i32x4*>(selp + i * 1024 + threadIdx.x * 4);

    // Stage 8 contiguous x rows (4096 floats) with coalesced float4 loads.
    const f32x4* xp4 = reinterpret_cast<const f32x4*>(x + (size_t)b0 * NN);
    f32x4* sh4 = reinterpret_cast<f32x4*>(xrows);
#pragma unroll
    for (int i = 0; i < (ROWS * NN / 4) / 256; ++i)   // 4 iterations
        sh4[i * 256 + threadIdx.x] = xp4[i * 256 + threadIdx.x];
    __syncthreads();

    float* op = out + (size_t)b0 * LO + chunk * CHUNK;

#pragma unroll
    for (int i = 0; i < ITERS; ++i) {
        const int base = i * 1024 + threadIdx.x * 4;

        // Phase 1: ALL 32 LDS gathers for this iter. Same 4 vaddrs for every
        // row; row offset r*NN is a compile-time immediate -> 32 independent
        // ds_read_b32, one coarse lgkmcnt wait instead of 8 fine ones.
        float v[ROWS][4];
#pragma unroll
        for (int r = 0; r < ROWS; ++r) {
            const float* row = xrows + r * NN;
            v[r][0] = row[s[i].x];
            v[r][1] = row[s[i].y];
            v[r][2] = row[s[i].z];
            v[r][3] = row[s[i].w];
        }

        // Phase 2: 8 back-to-back contiguous NT float4 stores.
#pragma unroll
        for (int r = 0; r < ROWS; ++r) {
            f32x4 t4 = {v[r][0], v[r][1], v[r][2], v[r][3]};
            __builtin_nontemporal_store(
                t4, reinterpret_cast<f32x4*>(op + (size_t)r * LO + base));
        }
    }
}

extern "C" void kernel_launch(void* const* d_in, const int* in_sizes, int n_in,
                              void* d_out, int out_size, void* d_ws, size_t ws_size,
                              hipStream_t stream) {
    const float* x       = (const float*)d_in[0];   // [B, N]
    const float* weights = (const float*)d_in[1];   // [C, L, O]
    const int*   indices = (const int*)d_in[2];     // [C, L, O] (int32: JAX x64 off)
    float*       out     = (float*)d_out;           // [B, L, O]
    int*         sel     = (int*)d_ws;              // [L*O] scratch (64 KiB)

    sel_kernel<<<LO / 64, 64, 0, stream>>>(weights, indices, sel);
    gather_kernel<<<(BB / ROWS) * NCHUNK, 256, 0, stream>>>(x, sel, out);
}

// Round 3
// 154.882 us; speedup vs baseline: 1.0097x; 1.0004x over previous
//
#include <hip/hip_runtime.h>

// Problem: B=2048, N=512, C=64, L=2, O=8192
//   connections = argmax_c weights[c,l,o]          -> [L,O]
//   sel[l,o]    = indices[connections[l,o], l, o]  -> [L,O]
//   out[b,l,o]  = x[b, sel[l,o]]                   -> [B,L,O] fp32 (128 MiB)
//
// R3 = INSTRUMENTATION ROUND. R0-R2 changes (occupancy, store order, NT,
// batched LDS reads) were all neutral; dur_us tracks the harness poison fill
// (residual stable at ~70.5 us). Cannot tell if gather is ~65 us (mystery
// mechanism) or ~27 us (near write floor, residual = reset dispatches).
// Fix the attribution: repeat gather's inner phase 4x (idempotent stores,
// memory clobber between reps). Delta(dur_us) = 3 x inner cost, and the
// dispatch becomes long enough (>83 us) to surface in rocprof top-5 with a
// full counter row. Revert REPEAT to 1 after reading the counters.

#define BB 2048
#define NN 512
#define CC 64
#define LL 2
#define OO 8192
#define LO (LL * OO)                   // 16384
#define ROWS 8                         // batch rows per block
#define CHUNK 2048                     // lo elements per block
#define NCHUNK (LO / CHUNK)            // 8  -> grid = 256*8 = 2048 blocks
#define ITERS (CHUNK / (256 * 4))      // 2 int4/float4 iterations per thread
#define REPEAT 4                       // instrumentation: x4 the inner phase

typedef float f32x4 __attribute__((ext_vector_type(4)));
typedef int   i32x4 __attribute__((ext_vector_type(4)));

__global__ void __launch_bounds__(64)
sel_kernel(const float* __restrict__ weights,
           const int* __restrict__ indices,
           int* __restrict__ sel) {
    int t = blockIdx.x * 64 + threadIdx.x;          // t = l*O + o; 256 blocks
    float best = weights[t];
    int bestc = 0;
#pragma unroll 16
    for (int c = 1; c < CC; ++c) {
        float w = weights[(size_t)c * LO + t];
        if (w > best) { best = w; bestc = c; }      // strict > = first-max (JAX argmax)
    }
    sel[t] = indices[(size_t)bestc * LO + t];
}

__global__ void __launch_bounds__(256, 8)
gather_kernel(const float* __restrict__ x,
              const int* __restrict__ sel,
              float* __restrict__ out) {
    __shared__ float xrows[ROWS * NN];   // 16 KiB: 8 contiguous batch rows of x

    const int chunk = blockIdx.x % NCHUNK;       // lo chunk  [0, 8)
    const int rg    = blockIdx.x / NCHUNK;       // row group [0, 256)
    const int b0    = rg * ROWS;

    // Issue sel loads first (independent of LDS) so they overlap x staging.
    i32x4 s[ITERS];
    const int* selp = sel + chunk * CHUNK;
#pragma unroll
    for (int i = 0; i < ITERS; ++i)
        s[i] = *reinterpret_cast<const i32x4*>(selp + i * 1024 + threadIdx.x * 4);

    // Stage 8 contiguous x rows (4096 floats) with coalesced float4 loads.
    const f32x4* xp4 = reinterpret_cast<const f32x4*>(x + (size_t)b0 * NN);
    f32x4* sh4 = reinterpret_cast<f32x4*>(xrows);
#pragma unroll
    for (int i = 0; i < (ROWS * NN / 4) / 256; ++i)   // 4 iterations
        sh4[i * 256 + threadIdx.x] = xp4[i * 256 + threadIdx.x];
    __syncthreads();

    float* op = out + (size_t)b0 * LO + chunk * CHUNK;

    for (int rep = 0; rep < REPEAT; ++rep) {
#pragma unroll
        for (int i = 0; i < ITERS; ++i) {
            const int base = i * 1024 + threadIdx.x * 4;

            // Phase 1: ALL 32 LDS gathers for this iter (one coarse wait).
            float v[ROWS][4];
#pragma unroll
            for (int r = 0; r < ROWS; ++r) {
                const float* row = xrows + r * NN;
                v[r][0] = row[s[i].x];
                v[r][1] = row[s[i].y];
                v[r][2] = row[s[i].z];
                v[r][3] = row[s[i].w];
            }

            // Phase 2: 8 back-to-back contiguous NT float4 stores.
#pragma unroll
            for (int r = 0; r < ROWS; ++r) {
                f32x4 t4 = {v[r][0], v[r][1], v[r][2], v[r][3]};
                __builtin_nontemporal_store(
                    t4, reinterpret_cast<f32x4*>(op + (size_t)r * LO + base));
            }
        }
        // Block cross-rep store elimination / LDS-read CSE.
        asm volatile("" ::: "memory");
    }
}

extern "C" void kernel_launch(void* const* d_in, const int* in_sizes, int n_in,
                              void* d_out, int out_size, void* d_ws, size_t ws_size,
                              hipStream_t stream) {
    const float* x       = (const float*)d_in[0];   // [B, N]
    const float* weights = (const float*)d_in[1];   // [C, L, O]
    const int*   indices = (const int*)d_in[2];     // [C, L, O] (int32: JAX x64 off)
    float*       out     = (float*)d_out;           // [B, L, O]
    int*         sel     = (int*)d_ws;              // [L*O] scratch (64 KiB)

    sel_kernel<<<LO / 64, 64, 0, stream>>>(weights, indices, sel);
    gather_kernel<<<(BB / ROWS) * NCHUNK, 256, 0, stream>>>(x, sel, out);
}

// Round 4
// 154.345 us; speedup vs baseline: 1.0132x; 1.0035x over previous
//
#include <hip/hip_runtime.h>

// Problem: B=2048, N=512, C=64, L=2, O=8192
//   connections = argmax_c weights[c,l,o]          -> [L,O]
//   sel[l,o]    = indices[connections[l,o], l, o]  -> [L,O]
//   out[b,l,o]  = x[b, sel[l,o]]                   -> [B,L,O] fp32 (128 MiB)
//
// FINAL (R4): R3's repeat-instrumentation + top-5-absence bound the gather at
// ~25 us (~= its 21 us write-roofline: 128 MiB @ 6.3 TB/s) and sel at ~4 us.
// The remaining ~125 us of dur_us is harness-fixed: 512 MiB poison fill
// (~84 us, itself at 80% HBM peak) + ~40 us reset dispatch overhead. All
// remaining kernel-side levers (<4 us) sit below the +-6 us fill noise.
// This version is R2's verified structure with instrumentation reverted.

#define BB 2048
#define NN 512
#define CC 64
#define LL 2
#define OO 8192
#define LO (LL * OO)                   // 16384
#define ROWS 8                         // batch rows per block
#define CHUNK 2048                     // lo elements per block
#define NCHUNK (LO / CHUNK)            // 8  -> grid = 256*8 = 2048 blocks (8/CU)
#define ITERS (CHUNK / (256 * 4))      // 2 int4/float4 iterations per thread

typedef float f32x4 __attribute__((ext_vector_type(4)));
typedef int   i32x4 __attribute__((ext_vector_type(4)));

__global__ void __launch_bounds__(64)
sel_kernel(const float* __restrict__ weights,
           const int* __restrict__ indices,
           int* __restrict__ sel) {
    int t = blockIdx.x * 64 + threadIdx.x;          // t = l*O + o; 256 blocks
    float best = weights[t];
    int bestc = 0;
#pragma unroll 16
    for (int c = 1; c < CC; ++c) {
        float w = weights[(size_t)c * LO + t];
        if (w > best) { best = w; bestc = c; }      // strict > = first-max (JAX argmax)
    }
    sel[t] = indices[(size_t)bestc * LO + t];
}

__global__ void __launch_bounds__(256, 8)
gather_kernel(const float* __restrict__ x,
              const int* __restrict__ sel,
              float* __restrict__ out) {
    __shared__ float xrows[ROWS * NN];   // 16 KiB: 8 contiguous batch rows of x

    const int chunk = blockIdx.x % NCHUNK;       // lo chunk  [0, 8)
    const int rg    = blockIdx.x / NCHUNK;       // row group [0, 256)
    const int b0    = rg * ROWS;

    // Issue sel loads first (independent of LDS) so they overlap x staging.
    i32x4 s[ITERS];
    const int* selp = sel + chunk * CHUNK;
#pragma unroll
    for (int i = 0; i < ITERS; ++i)
        s[i] = *reinterpret_cast<const i32x4*>(selp + i * 1024 + threadIdx.x * 4);

    // Stage 8 contiguous x rows (4096 floats) with coalesced float4 loads.
    const f32x4* xp4 = reinterpret_cast<const f32x4*>(x + (size_t)b0 * NN);
    f32x4* sh4 = reinterpret_cast<f32x4*>(xrows);
#pragma unroll
    for (int i = 0; i < (ROWS * NN / 4) / 256; ++i)   // 4 iterations
        sh4[i * 256 + threadIdx.x] = xp4[i * 256 + threadIdx.x];
    __syncthreads();

    float* op = out + (size_t)b0 * LO + chunk * CHUNK;

#pragma unroll
    for (int i = 0; i < ITERS; ++i) {
        const int base = i * 1024 + threadIdx.x * 4;

        // Phase 1: ALL 32 LDS gathers for this iter (one coarse lgkm wait).
        float v[ROWS][4];
#pragma unroll
        for (int r = 0; r < ROWS; ++r) {
            const float* row = xrows + r * NN;
            v[r][0] = row[s[i].x];
            v[r][1] = row[s[i].y];
            v[r][2] = row[s[i].z];
            v[r][3] = row[s[i].w];
        }

        // Phase 2: 8 back-to-back contiguous NT float4 stores.
#pragma unroll
        for (int r = 0; r < ROWS; ++r) {
            f32x4 t4 = {v[r][0], v[r][1], v[r][2], v[r][3]};
            __builtin_nontemporal_store(
                t4, reinterpret_cast<f32x4*>(op + (size_t)r * LO + base));
        }
    }
}

extern "C" void kernel_launch(void* const* d_in, const int* in_sizes, int n_in,
                              void* d_out, int out_size, void* d_ws, size_t ws_size,
                              hipStream_t stream) {
    const float* x       = (const float*)d_in[0];   // [B, N]
    const float* weights = (const float*)d_in[1];   // [C, L, O]
    const int*   indices = (const int*)d_in[2];     // [C, L, O] (int32: JAX x64 off)
    float*       out     = (float*)d_out;           // [B, L, O]
    int*         sel     = (int*)d_ws;              // [L*O] scratch (64 KiB)

    sel_kernel<<<LO / 64, 64, 0, stream>>>(weights, indices, sel);
    gather_kernel<<<(BB / ROWS) * NCHUNK, 256, 0, stream>>>(x, sel, out);
}